// Round 5
// baseline (405.258 us; speedup 1.0000x reference)
//
#include <hip/hip_runtime.h>
#include <math.h>

// Problem constants (from reference)
#define NWAY   10
#define DIMD   64
#define HWN    49           // H*W = 7*7
#define NSUP   800          // N_WAY*K_SHOT*PRJ
#define NQRY   16000        // N_WAY*Q_QUERY*PRJ
#define NTRI   2080         // 64*65/2
#define FEAT_PER (DIMD*HWN) // 3136 floats per sample
#define LDST   68           // fp32 dcov row stride (bank rotation, 16B-aligned)
#define KPAD   72           // bf16 row stride: 144 B/row, 16B-aligned frags
#define S0DIAG 3.16227766e-3f   // sqrt(1e-5): exact dcov diagonal

typedef __attribute__((ext_vector_type(8))) short bf16x8;
typedef __attribute__((ext_vector_type(4))) float f32x4;

struct __align__(16) BDCShared {
    union {
        float dcov[DIMD*LDST];                 // 17408 B (sqrt'd BDC matrix)
        unsigned short hl[2*DIMD*KPAD];        // 18432 B: H[64][72], L[64][72]
    } u;
    float dg[DIMD];
    float rmc[DIMD];        // rm[i] - tm/2  (so v = d - rmc_i - rmc_j)
    float psum[4*DIMD];     // per-wave column sums
    float red[4*NWAY];      // per-wave cross partials
    float red2[4];          // per-wave sum-of-squares partials
    float qq;               // sum_triu(v^2), closed form
};

// Map linear triu index k -> (i,j), j>=i, row-major triu of 64x64 (init only).
__device__ __forceinline__ void k2ij(int k, int& io, int& jo) {
    int ii = (int)floorf((129.0f - sqrtf(16641.0f - 8.0f*(float)k)) * 0.5f);
    int off = ii*(129-ii)/2;
    if (off > k) { --ii; off = ii*(129-ii)/2; }
    else {
        int off2 = (ii+1)*(128-ii)/2;
        if (off2 <= k) { ii += 1; off = off2; }
    }
    io = ii;
    jo = ii + (k - off);
}

// MFMA-based BDC: writes sqrt'd (uncentered) dcov into sm.u.dcov, centered
// row-means-minus-half-total into sm.rmc, qq (= sum_triu centered^2) into
// sm.qq. Block = 256 threads = 4 waves.
__device__ __forceinline__ void bdc_compute(const float* __restrict__ feat,
                                            float et, int sample,
                                            BDCShared& sm) {
    const int tid = threadIdx.x;
    unsigned short* H = sm.u.hl;
    unsigned short* Lp = sm.u.hl + DIMD*KPAD;

    // ---- Stage: fp32 -> (H,L) split by bit truncation (x = hf + l exactly;
    //      trunc(l) leaves residual ~2^-16|x| -> negligible after HL Gram).
    const float4* f4 = (const float4*)(feat + (size_t)sample * FEAT_PER);
    for (int idx = tid; idx < FEAT_PER/4; idx += 256) {
        float4 v = f4[idx];
        int e = idx * 4;
        #pragma unroll
        for (int kk = 0; kk < 4; ++kk) {
            int el = e + kk;
            int d = el / HWN;            // magic-div
            int m = el - d * HWN;
            float x = (&v.x)[kk];
            unsigned u = __float_as_uint(x);
            float l = x - __uint_as_float(u & 0xffff0000u);
            H[d*KPAD + m]  = (unsigned short)(u >> 16);
            Lp[d*KPAD + m] = (unsigned short)(__float_as_uint(l) >> 16);
        }
    }
    // zero-pad k = 49..63 (MFMA consumes K=64)
    for (int p = tid; p < DIMD*16; p += 256) {
        int d = p >> 4, k = 48 + (p & 15);
        if (k >= HWN) { H[d*KPAD + k] = 0; Lp[d*KPAD + k] = 0; }
    }
    __syncthreads();

    // ---- Gram via MFMA 16x16x32 bf16. Wave w owns G rows 16w..16w+15.
    const int wv = tid >> 6, lane = tid & 63;
    const int qd = lane >> 4, c15 = lane & 15;
    const int abase = (16*wv + c15)*KPAD + qd*8;
    bf16x8 AH0 = *(const bf16x8*)&H[abase];
    bf16x8 AH1 = *(const bf16x8*)&H[abase + 32];
    bf16x8 AL0 = *(const bf16x8*)&Lp[abase];
    bf16x8 AL1 = *(const bf16x8*)&Lp[abase + 32];

    f32x4 acc[4];
    #pragma unroll
    for (int J = 0; J < 4; ++J) {
        const int bbase = (16*J + c15)*KPAD + qd*8;
        bf16x8 BH0 = *(const bf16x8*)&H[bbase];
        bf16x8 BH1 = *(const bf16x8*)&H[bbase + 32];
        bf16x8 BL0 = *(const bf16x8*)&Lp[bbase];
        bf16x8 BL1 = *(const bf16x8*)&Lp[bbase + 32];
        f32x4 a = {0.f, 0.f, 0.f, 0.f};
        a = __builtin_amdgcn_mfma_f32_16x16x32_bf16(AH0, BH0, a, 0, 0, 0);
        a = __builtin_amdgcn_mfma_f32_16x16x32_bf16(AH1, BH1, a, 0, 0, 0);
        a = __builtin_amdgcn_mfma_f32_16x16x32_bf16(AL0, BH0, a, 0, 0, 0);
        a = __builtin_amdgcn_mfma_f32_16x16x32_bf16(AL1, BH1, a, 0, 0, 0);
        a = __builtin_amdgcn_mfma_f32_16x16x32_bf16(AH0, BL0, a, 0, 0, 0);
        a = __builtin_amdgcn_mfma_f32_16x16x32_bf16(AH1, BL1, a, 0, 0, 0);
        acc[J] = a;
    }

    // ---- dg from G diagonal (tile J == wv). C/D: col=lane&15, row=quad*4+reg.
    #pragma unroll
    for (int J = 0; J < 4; ++J) {
        if (J == wv) {
            #pragma unroll
            for (int r = 0; r < 4; ++r)
                if (c15 == 4*qd + r) sm.dg[16*wv + c15] = acc[J][r];
        }
    }
    __syncthreads();   // dg visible; all frag reads done -> union reuse safe

    // ---- dcov = sqrt(et*max(dg_i+dg_j-2g,0)+1e-5). Diag is exactly S0DIAG
    //      (val_ii == 0 since dg comes from the same MFMA G).
    float* dcov = sm.u.dcov;
    float dgi[4];
    #pragma unroll
    for (int r = 0; r < 4; ++r) dgi[r] = sm.dg[16*wv + 4*qd + r];
    #pragma unroll
    for (int J = 0; J < 4; ++J) {
        int j = 16*J + c15;
        float dgj = sm.dg[j];
        float4 w;
        #pragma unroll
        for (int r = 0; r < 4; ++r) {
            float val = dgi[r] + dgj - 2.0f*acc[J][r];
            (&w.x)[r] = __builtin_amdgcn_sqrtf(fmaf(et, fmaxf(val, 0.0f), 1e-5f));
        }
        // transpose-store: lane writes column j, rows 16wv+4qd..+3
        #pragma unroll
        for (int r = 0; r < 4; ++r)
            dcov[(16*wv + 4*qd + r)*LDST + j] = (&w.x)[r];
    }
    __syncthreads();

    // ---- column sums + sum of squares (d^2 for closed-form qq)
    {
        int c = tid & 63, q = tid >> 6;
        float s = 0.0f, sq = 0.0f;
        #pragma unroll
        for (int i2 = 0; i2 < 16; ++i2) {
            float d = dcov[(q*16 + i2)*LDST + c];
            s += d;
            sq = fmaf(d, d, sq);
        }
        sm.psum[q*DIMD + c] = s;
        // wave butterfly of sq -> red2[wave]
        #pragma unroll
        for (int o = 32; o > 0; o >>= 1) sq += __shfl_xor(sq, o, 64);
        if ((tid & 63) == 0) sm.red2[q] = sq;
    }
    __syncthreads();
    if (tid < DIMD) {     // wave 0 only
        int i = tid;
        float colsum = sm.psum[i] + sm.psum[DIMD+i] +
                       sm.psum[2*DIMD+i] + sm.psum[3*DIMD+i];
        float a = colsum * (1.0f/64.0f);
        float sa = a;
        #pragma unroll
        for (int o = 32; o > 0; o >>= 1) sa += __shfl_xor(sa, o, 64);
        float t = sa * (1.0f/64.0f);
        float rmc = a - 0.5f*t;
        sm.rmc[i] = rmc;
        float ci = S0DIAG - 2.0f*rmc;        // centered diagonal value
        float p  = a*a;                      // -> sum a^2
        float dd = ci*ci;                    // -> sum diag^2
        #pragma unroll
        for (int o = 32; o > 0; o >>= 1) {
            p  += __shfl_xor(p,  o, 64);
            dd += __shfl_xor(dd, o, 64);
        }
        if (tid == 0) {
            float sumd2 = sm.red2[0] + sm.red2[1] + sm.red2[2] + sm.red2[3];
            sm.qq = 0.5f*((sumd2 - 128.0f*p) + (4096.0f*t*t + dd));
        }
    }
    __syncthreads();
}

// init: zero support + loss slot, build triu table (addr<<16 | i<<8 | j)
__global__ void kern_init(float* __restrict__ support,
                          unsigned* __restrict__ table,
                          float* __restrict__ loss_slot) {
    int i = blockIdx.x * 256 + threadIdx.x;
    if (i < NWAY*NTRI) support[i] = 0.0f;
    if (i < NTRI) {
        int ii, jj; k2ij(i, ii, jj);
        table[i] = ((unsigned)(ii*LDST + jj) << 16) | ((unsigned)ii << 8) | (unsigned)jj;
    }
    if (i == 0) loss_slot[0] = 0.0f;
}

__global__ __launch_bounds__(256, 6) void kern_support(const float* __restrict__ feat,
                                                       const float* __restrict__ temp,
                                                       const unsigned* __restrict__ table,
                                                       float* __restrict__ support) {
    __shared__ BDCShared sm;
    float et = __expf(temp[0]);
    int s = blockIdx.x;                 // 0..799
    bdc_compute(feat, et, s, sm);
    const int tid = threadIdx.x;
    float* dst = support + (s / 80) * NTRI + tid;
    const unsigned* tb = table + tid;
    #pragma unroll
    for (int u = 0; u < 8; ++u) {
        unsigned t = tb[256*u];
        float v = sm.u.dcov[t >> 16] - sm.rmc[(t >> 8) & 63] - sm.rmc[t & 63];
        atomicAdd(&dst[256*u], v * (1.0f/80.0f));
    }
    if (tid < 32) {
        unsigned t = tb[2048];
        float v = sm.u.dcov[t >> 16] - sm.rmc[(t >> 8) & 63] - sm.rmc[t & 63];
        atomicAdd(&dst[2048], v * (1.0f/80.0f));
    }
}

// s2[m] = sum_triu S_m^2 (after support fully accumulated). Grid = NWAY.
__global__ __launch_bounds__(256) void kern_s2(const float* __restrict__ support,
                                               float* __restrict__ s2) {
    __shared__ float red[4];
    int m = blockIdx.x;
    const float* S = support + m * NTRI;
    float acc = 0.0f;
    for (int k = threadIdx.x; k < NTRI; k += 256) acc = fmaf(S[k], S[k], acc);
    int lane = threadIdx.x & 63, wv = threadIdx.x >> 6;
    #pragma unroll
    for (int o = 32; o > 0; o >>= 1) acc += __shfl_xor(acc, o, 64);
    if (lane == 0) red[wv] = acc;
    __syncthreads();
    if (threadIdx.x == 0) s2[m] = red[0] + red[1] + red[2] + red[3];
}

// Query: BDC -> score_m = -(qq + s2[m] - 2*cross[m])  (reference's own form)
__global__ __launch_bounds__(256, 6) void kern_query(const float* __restrict__ feat,
                                                     const float* __restrict__ temp,
                                                     const unsigned* __restrict__ table,
                                                     const float* __restrict__ support,
                                                     const float* __restrict__ s2,
                                                     float* __restrict__ out) {
    __shared__ BDCShared sm;
    float et = __expf(temp[0]);
    int qn = blockIdx.x;                // 0..15999
    bdc_compute(feat, et, NSUP + qn, sm);
    const int tid = threadIdx.x;

    float cr[NWAY];
    #pragma unroll
    for (int m = 0; m < NWAY; ++m) cr[m] = 0.0f;

    const unsigned* tb = table + tid;
    const float* sp = support + tid;
    #pragma unroll
    for (int u = 0; u < 8; ++u) {
        unsigned t = tb[256*u];
        float v = sm.u.dcov[t >> 16] - sm.rmc[(t >> 8) & 63] - sm.rmc[t & 63];
        #pragma unroll
        for (int m = 0; m < NWAY; ++m)
            cr[m] = fmaf(v, sp[m*NTRI + 256*u], cr[m]);
    }
    if (tid < 32) {
        unsigned t = tb[2048];
        float v = sm.u.dcov[t >> 16] - sm.rmc[(t >> 8) & 63] - sm.rmc[t & 63];
        #pragma unroll
        for (int m = 0; m < NWAY; ++m)
            cr[m] = fmaf(v, sp[m*NTRI + 2048], cr[m]);
    }

    // reduce 10 accumulators: wave butterfly + cross-wave via LDS
    int lane = tid & 63, wv = tid >> 6;
    #pragma unroll
    for (int m = 0; m < NWAY; ++m) {
        float v = cr[m];
        #pragma unroll
        for (int o = 32; o > 0; o >>= 1) v += __shfl_xor(v, o, 64);
        cr[m] = v;
    }
    if (lane == 0) {
        #pragma unroll
        for (int m = 0; m < NWAY; ++m) sm.red[wv*NWAY + m] = cr[m];
    }
    __syncthreads();
    if (tid < NWAY) {
        int m = tid;
        float CR = sm.red[m] + sm.red[NWAY+m] + sm.red[2*NWAY+m] + sm.red[3*NWAY+m];
        out[(size_t)qn * NWAY + m] = -(sm.qq + s2[m] - 2.0f*CR);
    }
}

// Softmax NLL partials: one atomicAdd per block.
__global__ __launch_bounds__(256) void kern_loss(const float* __restrict__ score,
                                                 const int* __restrict__ label,
                                                 float* __restrict__ loss_out) {
    __shared__ float red[4];
    int n = blockIdx.x * 256 + threadIdx.x;
    float lsum = 0.0f;
    if (n < NQRY) {
        const float* srow = score + (size_t)n * NWAY;
        float s[NWAY];
        float mx = -1e30f;
        #pragma unroll
        for (int m = 0; m < NWAY; ++m) { s[m] = srow[m]; mx = fmaxf(mx, s[m]); }
        float se = 0.0f;
        #pragma unroll
        for (int m = 0; m < NWAY; ++m) se += __expf(s[m] - mx);
        float lse = mx + __logf(se);
        lsum = lse - s[label[n]];
    }
    int lane = threadIdx.x & 63, wv = threadIdx.x >> 6;
    #pragma unroll
    for (int o = 32; o > 0; o >>= 1) lsum += __shfl_xor(lsum, o, 64);
    if (lane == 0) red[wv] = lsum;
    __syncthreads();
    if (threadIdx.x == 0)
        atomicAdd(loss_out, (red[0] + red[1] + red[2] + red[3]) * (1.0f / (float)NQRY));
}

extern "C" void kernel_launch(void* const* d_in, const int* in_sizes, int n_in,
                              void* d_out, int out_size, void* d_ws, size_t ws_size,
                              hipStream_t stream) {
    const float* feat = (const float*)d_in[0];
    const float* temp = (const float*)d_in[1];
    const int*   label = (const int*)d_in[2];
    float* out = (float*)d_out;

    float*    support = (float*)d_ws;                        // 20800 f
    float*    s2      = support + NWAY*NTRI;                 // 10 f
    unsigned* table   = (unsigned*)(s2 + 16);                // 2080 u32
    float* loss_slot  = out + (size_t)NQRY * NWAY;

    kern_init<<<(NWAY*NTRI + 255)/256, 256, 0, stream>>>(support, table, loss_slot);
    kern_support<<<NSUP, 256, 0, stream>>>(feat, temp, table, support);
    kern_s2<<<NWAY, 256, 0, stream>>>(support, s2);
    kern_query<<<NQRY, 256, 0, stream>>>(feat, temp, table, support, s2, out);
    kern_loss<<<(NQRY + 255)/256, 256, 0, stream>>>(out, label, loss_slot);
}

// Round 6
// 387.433 us; speedup vs baseline: 1.0460x; 1.0460x over previous
//
#include <hip/hip_runtime.h>
#include <math.h>

// Problem constants (from reference)
#define NWAY   10
#define DIMD   64
#define HWN    49           // H*W = 7*7
#define NSUP   800          // N_WAY*K_SHOT*PRJ
#define NQRY   16000        // N_WAY*Q_QUERY*PRJ
#define NTRI   2080         // 64*65/2
#define FEAT_PER (DIMD*HWN) // 3136 floats per sample
#define LDST   68           // fp32 dcov row stride (bank rotation, 16B-aligned)
#define KPAD   72           // bf16 row stride: 144 B/row, 16B-aligned frags
#define S0DIAG 3.16227766e-3f   // sqrt(1e-5): exact dcov diagonal

typedef __attribute__((ext_vector_type(8))) short bf16x8;
typedef __attribute__((ext_vector_type(4))) float f32x4;

struct __align__(16) BDCShared {
    union {
        float dcov[DIMD*LDST];                 // 17408 B (sqrt'd BDC matrix)
        unsigned short hl[2*DIMD*KPAD];        // 18432 B: H[64][72], L[64][72]
    } u;
    float dg[DIMD];
    float rmc[DIMD];        // rm[i] - tm/2  (so v = d - rmc_i - rmc_j)
    float psum[4*DIMD];     // per-wave column sums
    float red[4*NWAY];      // per-wave cross partials
    float red2[4];          // per-wave sum-of-squares partials
    float qq;               // sum_triu(v^2), closed form
};

// Map linear triu index k -> (i,j), j>=i, row-major triu of 64x64 (init only).
__device__ __forceinline__ void k2ij(int k, int& io, int& jo) {
    int ii = (int)floorf((129.0f - sqrtf(16641.0f - 8.0f*(float)k)) * 0.5f);
    int off = ii*(129-ii)/2;
    if (off > k) { --ii; off = ii*(129-ii)/2; }
    else {
        int off2 = (ii+1)*(128-ii)/2;
        if (off2 <= k) { ii += 1; off = off2; }
    }
    io = ii;
    jo = ii + (k - off);
}

// MFMA-based BDC: writes sqrt'd (uncentered) dcov into sm.u.dcov, centered
// row-means-minus-half-total into sm.rmc, qq (= sum_triu centered^2) into
// sm.qq. Block = 256 threads = 4 waves.
__device__ __forceinline__ void bdc_compute(const float* __restrict__ feat,
                                            float et, int sample,
                                            BDCShared& sm) {
    const int tid = threadIdx.x;
    unsigned short* H = sm.u.hl;
    unsigned short* Lp = sm.u.hl + DIMD*KPAD;

    // ---- Stage: fp32 -> (H,L) split by bit truncation (x = hf + l exactly;
    //      trunc(l) leaves residual ~2^-16|x| -> negligible after HL Gram).
    const float4* f4 = (const float4*)(feat + (size_t)sample * FEAT_PER);
    for (int idx = tid; idx < FEAT_PER/4; idx += 256) {
        float4 v = f4[idx];
        int e = idx * 4;
        #pragma unroll
        for (int kk = 0; kk < 4; ++kk) {
            int el = e + kk;
            int d = el / HWN;            // magic-div
            int m = el - d * HWN;
            float x = (&v.x)[kk];
            unsigned u = __float_as_uint(x);
            float l = x - __uint_as_float(u & 0xffff0000u);
            H[d*KPAD + m]  = (unsigned short)(u >> 16);
            Lp[d*KPAD + m] = (unsigned short)(__float_as_uint(l) >> 16);
        }
    }
    // zero-pad k = 49..63 (MFMA consumes K=64)
    for (int p = tid; p < DIMD*16; p += 256) {
        int d = p >> 4, k = 48 + (p & 15);
        if (k >= HWN) { H[d*KPAD + k] = 0; Lp[d*KPAD + k] = 0; }
    }
    __syncthreads();

    // ---- Gram via MFMA 16x16x32 bf16. Wave w owns G rows 16w..16w+15.
    const int wv = tid >> 6, lane = tid & 63;
    const int qd = lane >> 4, c15 = lane & 15;
    const int abase = (16*wv + c15)*KPAD + qd*8;
    bf16x8 AH0 = *(const bf16x8*)&H[abase];
    bf16x8 AH1 = *(const bf16x8*)&H[abase + 32];
    bf16x8 AL0 = *(const bf16x8*)&Lp[abase];
    bf16x8 AL1 = *(const bf16x8*)&Lp[abase + 32];

    f32x4 acc[4];
    #pragma unroll
    for (int J = 0; J < 4; ++J) {
        const int bbase = (16*J + c15)*KPAD + qd*8;
        bf16x8 BH0 = *(const bf16x8*)&H[bbase];
        bf16x8 BH1 = *(const bf16x8*)&H[bbase + 32];
        bf16x8 BL0 = *(const bf16x8*)&Lp[bbase];
        bf16x8 BL1 = *(const bf16x8*)&Lp[bbase + 32];
        f32x4 a = {0.f, 0.f, 0.f, 0.f};
        a = __builtin_amdgcn_mfma_f32_16x16x32_bf16(AH0, BH0, a, 0, 0, 0);
        a = __builtin_amdgcn_mfma_f32_16x16x32_bf16(AH1, BH1, a, 0, 0, 0);
        a = __builtin_amdgcn_mfma_f32_16x16x32_bf16(AL0, BH0, a, 0, 0, 0);
        a = __builtin_amdgcn_mfma_f32_16x16x32_bf16(AL1, BH1, a, 0, 0, 0);
        a = __builtin_amdgcn_mfma_f32_16x16x32_bf16(AH0, BL0, a, 0, 0, 0);
        a = __builtin_amdgcn_mfma_f32_16x16x32_bf16(AH1, BL1, a, 0, 0, 0);
        acc[J] = a;
    }

    // ---- dg from G diagonal (tile J == wv). C/D: col=lane&15, row=quad*4+reg.
    #pragma unroll
    for (int J = 0; J < 4; ++J) {
        if (J == wv) {
            #pragma unroll
            for (int r = 0; r < 4; ++r)
                if (c15 == 4*qd + r) sm.dg[16*wv + c15] = acc[J][r];
        }
    }
    __syncthreads();   // dg visible; all frag reads done -> union reuse safe

    // ---- dcov = sqrt(et*max(dg_i+dg_j-2g,0)+1e-5). Diag is exactly S0DIAG
    //      (val_ii == 0 since dg comes from the same MFMA G).
    float* dcov = sm.u.dcov;
    float dgi[4];
    #pragma unroll
    for (int r = 0; r < 4; ++r) dgi[r] = sm.dg[16*wv + 4*qd + r];
    #pragma unroll
    for (int J = 0; J < 4; ++J) {
        int j = 16*J + c15;
        float dgj = sm.dg[j];
        #pragma unroll
        for (int r = 0; r < 4; ++r) {
            float val = dgi[r] + dgj - 2.0f*acc[J][r];
            dcov[(16*wv + 4*qd + r)*LDST + j] =
                __builtin_amdgcn_sqrtf(fmaf(et, fmaxf(val, 0.0f), 1e-5f));
        }
    }
    __syncthreads();

    // ---- column sums + sum of squares (d^2 for closed-form qq)
    {
        int c = tid & 63, q = tid >> 6;
        float s = 0.0f, sq = 0.0f;
        #pragma unroll
        for (int i2 = 0; i2 < 16; ++i2) {
            float d = dcov[(q*16 + i2)*LDST + c];
            s += d;
            sq = fmaf(d, d, sq);
        }
        sm.psum[q*DIMD + c] = s;
        // wave butterfly of sq -> red2[wave]
        #pragma unroll
        for (int o = 32; o > 0; o >>= 1) sq += __shfl_xor(sq, o, 64);
        if ((tid & 63) == 0) sm.red2[q] = sq;
    }
    __syncthreads();
    if (tid < DIMD) {     // wave 0 only
        int i = tid;
        float colsum = sm.psum[i] + sm.psum[DIMD+i] +
                       sm.psum[2*DIMD+i] + sm.psum[3*DIMD+i];
        float a = colsum * (1.0f/64.0f);
        float sa = a;
        #pragma unroll
        for (int o = 32; o > 0; o >>= 1) sa += __shfl_xor(sa, o, 64);
        float t = sa * (1.0f/64.0f);
        float rmc = a - 0.5f*t;
        sm.rmc[i] = rmc;
        float ci = S0DIAG - 2.0f*rmc;        // centered diagonal value
        float p  = a*a;                      // -> sum a^2
        float dd = ci*ci;                    // -> sum diag^2
        #pragma unroll
        for (int o = 32; o > 0; o >>= 1) {
            p  += __shfl_xor(p,  o, 64);
            dd += __shfl_xor(dd, o, 64);
        }
        if (tid == 0) {
            float sumd2 = sm.red2[0] + sm.red2[1] + sm.red2[2] + sm.red2[3];
            sm.qq = 0.5f*((sumd2 - 128.0f*p) + (4096.0f*t*t + dd));
        }
    }
    __syncthreads();
}

// init: zero support + loss slot, build triu table (addr<<16 | i<<8 | j)
__global__ void kern_init(float* __restrict__ support,
                          unsigned* __restrict__ table,
                          float* __restrict__ loss_slot) {
    int i = blockIdx.x * 256 + threadIdx.x;
    if (i < NWAY*NTRI) support[i] = 0.0f;
    if (i < NTRI) {
        int ii, jj; k2ij(i, ii, jj);
        table[i] = ((unsigned)(ii*LDST + jj) << 16) | ((unsigned)ii << 8) | (unsigned)jj;
    }
    if (i == 0) loss_slot[0] = 0.0f;
}

__global__ __launch_bounds__(256, 6) void kern_support(const float* __restrict__ feat,
                                                       const float* __restrict__ temp,
                                                       const unsigned* __restrict__ table,
                                                       float* __restrict__ support) {
    __shared__ BDCShared sm;
    float et = __expf(temp[0]);
    int s = blockIdx.x;                 // 0..799
    bdc_compute(feat, et, s, sm);
    float* dst = support + (s / 80) * NTRI;
    // plain strided loop: low register pressure, no spill (R5 lesson)
    for (int k = threadIdx.x; k < NTRI; k += 256) {
        unsigned t = table[k];
        float v = sm.u.dcov[t >> 16] - sm.rmc[(t >> 8) & 63] - sm.rmc[t & 63];
        atomicAdd(&dst[k], v * (1.0f/80.0f));
    }
}

// s2[m] = sum_triu S_m^2 (after support fully accumulated). Grid = NWAY.
__global__ __launch_bounds__(256) void kern_s2(const float* __restrict__ support,
                                               float* __restrict__ s2) {
    __shared__ float red[4];
    int m = blockIdx.x;
    const float* S = support + m * NTRI;
    float acc = 0.0f;
    for (int k = threadIdx.x; k < NTRI; k += 256) acc = fmaf(S[k], S[k], acc);
    int lane = threadIdx.x & 63, wv = threadIdx.x >> 6;
    #pragma unroll
    for (int o = 32; o > 0; o >>= 1) acc += __shfl_xor(acc, o, 64);
    if (lane == 0) red[wv] = acc;
    __syncthreads();
    if (threadIdx.x == 0) s2[m] = red[0] + red[1] + red[2] + red[3];
}

// Query: BDC -> score_m = -(qq + s2[m] - 2*cross[m])  (reference's own form)
__global__ __launch_bounds__(256, 6) void kern_query(const float* __restrict__ feat,
                                                     const float* __restrict__ temp,
                                                     const unsigned* __restrict__ table,
                                                     const float* __restrict__ support,
                                                     const float* __restrict__ s2,
                                                     float* __restrict__ out) {
    __shared__ BDCShared sm;
    float et = __expf(temp[0]);
    int qn = blockIdx.x;                // 0..15999
    bdc_compute(feat, et, NSUP + qn, sm);
    const int tid = threadIdx.x;

    float cr[NWAY];
    #pragma unroll
    for (int m = 0; m < NWAY; ++m) cr[m] = 0.0f;

    // plain strided loop (R4 structure): ~16 live regs, no spill.
    for (int k = tid; k < NTRI; k += 256) {
        unsigned t = table[k];
        float v = sm.u.dcov[t >> 16] - sm.rmc[(t >> 8) & 63] - sm.rmc[t & 63];
        #pragma unroll
        for (int m = 0; m < NWAY; ++m)
            cr[m] = fmaf(v, support[m*NTRI + k], cr[m]);
    }

    // reduce 10 accumulators: wave butterfly + cross-wave via LDS
    int lane = tid & 63, wv = tid >> 6;
    #pragma unroll
    for (int m = 0; m < NWAY; ++m) {
        float v = cr[m];
        #pragma unroll
        for (int o = 32; o > 0; o >>= 1) v += __shfl_xor(v, o, 64);
        cr[m] = v;
    }
    if (lane == 0) {
        #pragma unroll
        for (int m = 0; m < NWAY; ++m) sm.red[wv*NWAY + m] = cr[m];
    }
    __syncthreads();
    if (tid < NWAY) {
        int m = tid;
        float CR = sm.red[m] + sm.red[NWAY+m] + sm.red[2*NWAY+m] + sm.red[3*NWAY+m];
        out[(size_t)qn * NWAY + m] = -(sm.qq + s2[m] - 2.0f*CR);
    }
}

// Softmax NLL partials: one atomicAdd per block.
__global__ __launch_bounds__(256) void kern_loss(const float* __restrict__ score,
                                                 const int* __restrict__ label,
                                                 float* __restrict__ loss_out) {
    __shared__ float red[4];
    int n = blockIdx.x * 256 + threadIdx.x;
    float lsum = 0.0f;
    if (n < NQRY) {
        const float* srow = score + (size_t)n * NWAY;
        float s[NWAY];
        float mx = -1e30f;
        #pragma unroll
        for (int m = 0; m < NWAY; ++m) { s[m] = srow[m]; mx = fmaxf(mx, s[m]); }
        float se = 0.0f;
        #pragma unroll
        for (int m = 0; m < NWAY; ++m) se += __expf(s[m] - mx);
        float lse = mx + __logf(se);
        lsum = lse - s[label[n]];
    }
    int lane = threadIdx.x & 63, wv = threadIdx.x >> 6;
    #pragma unroll
    for (int o = 32; o > 0; o >>= 1) lsum += __shfl_xor(lsum, o, 64);
    if (lane == 0) red[wv] = lsum;
    __syncthreads();
    if (threadIdx.x == 0)
        atomicAdd(loss_out, (red[0] + red[1] + red[2] + red[3]) * (1.0f / (float)NQRY));
}

extern "C" void kernel_launch(void* const* d_in, const int* in_sizes, int n_in,
                              void* d_out, int out_size, void* d_ws, size_t ws_size,
                              hipStream_t stream) {
    const float* feat = (const float*)d_in[0];
    const float* temp = (const float*)d_in[1];
    const int*   label = (const int*)d_in[2];
    float* out = (float*)d_out;

    float*    support = (float*)d_ws;                        // 20800 f
    float*    s2      = support + NWAY*NTRI;                 // 10 f
    unsigned* table   = (unsigned*)(s2 + 16);                // 2080 u32
    float* loss_slot  = out + (size_t)NQRY * NWAY;

    kern_init<<<(NWAY*NTRI + 255)/256, 256, 0, stream>>>(support, table, loss_slot);
    kern_support<<<NSUP, 256, 0, stream>>>(feat, temp, table, support);
    kern_s2<<<NWAY, 256, 0, stream>>>(support, s2);
    kern_query<<<NQRY, 256, 0, stream>>>(feat, temp, table, support, s2, out);
    kern_loss<<<(NQRY + 255)/256, 256, 0, stream>>>(out, label, loss_slot);
}